// Round 20
// baseline (118.746 us; speedup 1.0000x reference)
//
#include <hip/hip_runtime.h>

#define L2E 1.44269504088896340736f   // log2(e)
#define LN2 0.69314718055994530942f

// Raw HW transcendentals: v_exp_f32 = 2^x, v_log_f32 = log2(x).
#define EXP2F(x) __builtin_amdgcn_exp2f(x)
#define LOG2F(x) __builtin_amdgcn_logf(x)

// TWO DPs PER WAVE IN PARALLEL LANES: lanes 0-31 = batch b, lanes 32-63 =
// batch b+256; lane l (= t&31) owns rows 8l..8l+7 of its batch.
// R11-R19 synthesis: all structures converge to ~330cy/step because the
// cost is per-step exposed latency at wait points (1 wave/SIMD), not line
// throughput (R19: 4x fewer lines, no change) nor pipeline depth (R12).
// Packing 2 DPs into one wave's lanes retires 2 diagonals per stall.
// w-domain math (verified R12/R17): w = 2^(sig-E), w_new = g*(wa+wb+wc),
// g = 2^(-C*l2e), BIG == 0.  Per step kk (P = kk&3, SB = (kk>>2)&1):
// rows P (bank SB) and P+4 (bank 1-SB) rotate: c<-n, n<-g4(slot), slot<-
// load(col cl(kk+12-i-l8)); conversion col u_i = kk+4-i-l8, junk iff
// u > 252.  g_i = comp<(P-i)&3>(c_i); e_i = g_i*(w1_i + w1_{i-1} +
// w2_{i-1}); lane boundary via ONE shfl_up(e7) (computed FIRST so its
// latency hides), masked at l==0.  Renorm every 64 diagonals per 32-lane
// half (shfl_xor 1..16), exact 2^-e, sig -= e.

typedef float f4 __attribute__((ext_vector_type(4)));

template <int I> __device__ __forceinline__ float comp(const f4 v) {
    if constexpr (I == 0) return v.x;
    else if constexpr (I == 1) return v.y;
    else if constexpr (I == 2) return v.z;
    else return v.w;
}

__device__ __forceinline__ f4 g4f(const f4 v) {
    f4 r;
    r.x = EXP2F(v.x * -L2E); r.y = EXP2F(v.y * -L2E);
    r.z = EXP2F(v.z * -L2E); r.w = EXP2F(v.w * -L2E);
    return r;
}

template <int P, int SB>
__device__ __forceinline__ void stepf(
    int kk, int l, int l8, const float* __restrict__ RP,
    f4& c0, f4& c1, f4& c2, f4& c3, f4& c4, f4& c5, f4& c6, f4& c7,
    f4& n0, f4& n1, f4& n2, f4& n3, f4& n4, f4& n5, f4& n6, f4& n7,
    f4& a0, f4& a1, f4& a2, f4& a3, f4& a4, f4& a5, f4& a6, f4& a7,
    f4& b0, f4& b1, f4& b2, f4& b3, f4& b4, f4& b5, f4& b6, f4& b7,
    float& w10, float& w11, float& w12, float& w13,
    float& w14, float& w15, float& w16, float& w17,
    float& w20, float& w21, float& w22, float& w23,
    float& w24, float& w25, float& w26, float& w27,
    float& pd1, float& pd2)
{
    constexpr int RL = P;        // low row refilled this step, bank SB
    constexpr int RH = P + 4;    // high row, bank 1-SB

    const int uLo = kk + 4 - P - l8;   // col of quad converted for row P
    const int uHi = uLo - 4;           // for row P+4
    const int cL0 = uLo + 8, cH0 = uHi + 8;
    const int colLo = cL0 < 0 ? 0 : (cL0 > 252 ? 252 : cL0);
    const int colHi = cH0 < 0 ? 0 : (cH0 > 252 ? 252 : cH0);

    f4& sLo = (SB == 0) ? ((RL == 0) ? a0 : (RL == 1) ? a1 : (RL == 2) ? a2 : a3)
                        : ((RL == 0) ? b0 : (RL == 1) ? b1 : (RL == 2) ? b2 : b3);
    f4& sHi = (SB == 0) ? ((RH == 4) ? b4 : (RH == 5) ? b5 : (RH == 6) ? b6 : b7)
                        : ((RH == 4) ? a4 : (RH == 5) ? a5 : (RH == 6) ? a6 : a7);
    f4& cLr = (RL == 0) ? c0 : (RL == 1) ? c1 : (RL == 2) ? c2 : c3;
    f4& nLr = (RL == 0) ? n0 : (RL == 1) ? n1 : (RL == 2) ? n2 : n3;
    f4& cHr = (RH == 4) ? c4 : (RH == 5) ? c5 : (RH == 6) ? c6 : c7;
    f4& nHr = (RH == 4) ? n4 : (RH == 5) ? n5 : (RH == 6) ? n6 : n7;

    // conversions (slots loaded 8 steps ago); junk-zero past col 252
    const bool jLo = (uLo > 252), jHi = (uHi > 252);
    f4 gLo, gHi;
    gLo.x = jLo ? 0.0f : EXP2F(sLo.x * -L2E);
    gLo.y = jLo ? 0.0f : EXP2F(sLo.y * -L2E);
    gLo.z = jLo ? 0.0f : EXP2F(sLo.z * -L2E);
    gLo.w = jLo ? 0.0f : EXP2F(sLo.w * -L2E);
    gHi.x = jHi ? 0.0f : EXP2F(sHi.x * -L2E);
    gHi.y = jHi ? 0.0f : EXP2F(sHi.y * -L2E);
    gHi.z = jHi ? 0.0f : EXP2F(sHi.z * -L2E);
    gHi.w = jHi ? 0.0f : EXP2F(sHi.w * -L2E);
    cLr = nLr; nLr = gLo;
    cHr = nHr; nHr = gHi;
    sLo = *(const f4*)(RP + RL * 256 + colLo);
    sHi = *(const f4*)(RP + RH * 256 + colHi);

    // cells; e7 + shfl FIRST so ds_bpermute latency hides under the rest
    const float g7 = comp<((P - 7) & 3)>(c7);
    const float e7 = g7 * (w17 + w16 + w26);
    const float nx = __shfl_up(e7, 1);
    const float g0 = comp<((P - 0) & 3)>(c0);
    const float g1 = comp<((P - 1) & 3)>(c1);
    const float g2 = comp<((P - 2) & 3)>(c2);
    const float g3 = comp<((P - 3) & 3)>(c3);
    const float g4v = comp<((P - 4) & 3)>(c4);
    const float g5 = comp<((P - 5) & 3)>(c5);
    const float g6 = comp<((P - 6) & 3)>(c6);
    const float e0 = g0 * (w10 + pd1 + pd2);
    const float e1 = g1 * (w11 + w10 + w20);
    const float e2 = g2 * (w12 + w11 + w21);
    const float e3 = g3 * (w13 + w12 + w22);
    const float e4 = g4v * (w14 + w13 + w23);
    const float e5 = g5 * (w15 + w14 + w24);
    const float e6 = g6 * (w16 + w15 + w25);

    w20 = w10; w21 = w11; w22 = w12; w23 = w13;
    w24 = w14; w25 = w15; w26 = w16; w27 = w17;
    w10 = e0; w11 = e1; w12 = e2; w13 = e3;
    w14 = e4; w15 = e5; w16 = e6; w17 = e7;

    pd2 = pd1;
    pd1 = (l == 0) ? 0.0f : nx;

    asm volatile("" ::: "memory");   // step boundary (no insts, pins order)
}

__global__ __launch_bounds__(64, 1) void dp_softmin_wave(const float* __restrict__ C,
                                                         float* __restrict__ out) {
    const int bb = blockIdx.x;             // 0..255
    const int t = threadIdx.x;
    const int h = t >> 5;                  // half: 0 -> batch bb, 1 -> bb+256
    const int l = t & 31;                  // lane within DP
    const int l8 = l << 3;                 // first owned row
    const float* Cb = C + (((size_t)bb + ((size_t)h << 8)) << 16);
    const float* RP = Cb + ((size_t)l8 << 8);   // row-base pointer

    auto cl = [](int c) { return c < 0 ? 0 : (c > 252 ? 252 : c); };
    auto q  = [&](int i, int col) { return *(const f4*)(RP + i * 256 + col); };

    // init = fixed point of the unconditional machine for kk <= 0
    f4 c0 = g4f(q(0, 0)), c1 = g4f(q(1, 0)), c2 = g4f(q(2, 0)), c3 = g4f(q(3, 0)),
       c4 = g4f(q(4, 0)), c5 = g4f(q(5, 0)), c6 = g4f(q(6, 0)), c7 = g4f(q(7, 0));
    f4 n0 = g4f(q(0, cl(4 - l8)));
    f4 n1 = c1, n2 = c2, n3 = c3, n4 = c4, n5 = c5, n6 = c6, n7 = c7;

    // slot banks (hand-derived virtual-refill init; verified kk=1,4,8)
    f4 a0 = q(0, cl(12 - l8)), b0 = q(0, cl(8 - l8));
    f4 a1 = q(1, cl(4 - l8)),  b1 = q(1, cl(8 - l8));
    f4 a2 = q(2, cl(4 - l8)),  b2 = q(2, cl(8 - l8));
    f4 a3 = q(3, cl(4 - l8)),  b3 = q(3, cl(8 - l8));
    f4 a4 = q(4, cl(4 - l8)),  b4 = q(4, cl(8 - l8));
    f4 a5 = q(5, cl(4 - l8)),  b5 = q(5, cl(0 - l8));
    f4 a6 = q(6, cl(4 - l8)),  b6 = q(6, cl(0 - l8));
    f4 a7 = q(7, cl(4 - l8)),  b7 = q(7, cl(0 - l8));

    float w10 = 0.f, w11 = 0.f, w12 = 0.f, w13 = 0.f,
          w14 = 0.f, w15 = 0.f, w16 = 0.f, w17 = 0.f;
    float w20 = 0.f, w21 = 0.f, w22 = 0.f, w23 = 0.f,
          w24 = 0.f, w25 = 0.f, w26 = 0.f, w27 = 0.f;
    float pd1 = 0.f, pd2 = 0.f;
    int sig = 0;
    if (l == 0) w10 = c0.x;                // seed w(0,0) = g(0,0), both halves

#define ARGS l, l8, RP, c0,c1,c2,c3,c4,c5,c6,c7, n0,n1,n2,n3,n4,n5,n6,n7, \
             a0,a1,a2,a3,a4,a5,a6,a7, b0,b1,b2,b3,b4,b5,b6,b7, \
             w10,w11,w12,w13,w14,w15,w16,w17, w20,w21,w22,w23,w24,w25,w26,w27, \
             pd1,pd2

    // prologue kk = 1..7
    stepf<1,0>(1, ARGS); stepf<2,0>(2, ARGS); stepf<3,0>(3, ARGS);
    stepf<0,1>(4, ARGS); stepf<1,1>(5, ARGS); stepf<2,1>(6, ARGS); stepf<3,1>(7, ARGS);

#pragma clang loop unroll(disable)
    for (int kb = 8; kb <= 496; kb += 8) {
        if ((kb & 63) == 0) {
            // per-half block-floating renorm (shfl_xor 1..16 stays in-half)
            float M = fmaxf(
                fmaxf(fmaxf(fmaxf(w10, w11), fmaxf(w12, w13)),
                      fmaxf(fmaxf(w14, w15), fmaxf(w16, w17))),
                fmaxf(fmaxf(fmaxf(w20, w21), fmaxf(w22, w23)),
                      fmaxf(fmaxf(w24, w25), fmaxf(w26, w27))));
            #pragma unroll
            for (int m = 1; m < 32; m <<= 1) M = fmaxf(M, __shfl_xor(M, m));
            int e = ((__float_as_int(M) >> 23) & 255) - 127;
            float f = __int_as_float((127 - e) << 23);
            w10 *= f; w11 *= f; w12 *= f; w13 *= f;
            w14 *= f; w15 *= f; w16 *= f; w17 *= f;
            w20 *= f; w21 *= f; w22 *= f; w23 *= f;
            w24 *= f; w25 *= f; w26 *= f; w27 *= f;
            pd1 *= f; pd2 *= f;
            sig -= e;
        }
        stepf<0,0>(kb + 0, ARGS); stepf<1,0>(kb + 1, ARGS);
        stepf<2,0>(kb + 2, ARGS); stepf<3,0>(kb + 3, ARGS);
        stepf<0,1>(kb + 4, ARGS); stepf<1,1>(kb + 5, ARGS);
        stepf<2,1>(kb + 6, ARGS); stepf<3,1>(kb + 7, ARGS);
    }

    // epilogue kk = 504..510
    stepf<0,0>(504, ARGS); stepf<1,0>(505, ARGS); stepf<2,0>(506, ARGS);
    stepf<3,0>(507, ARGS); stepf<0,1>(508, ARGS); stepf<1,1>(509, ARGS);
    stepf<2,1>(510, ARGS);
#undef ARGS

    // corner (255,255): lane 31 (batch bb) / lane 63 (batch bb+256), w17
    if (l == 31) {
        const float d = ((float)sig - LOG2F(w17)) * LN2;
        out[bb + (h << 8)] = d;
    }
}

extern "C" void kernel_launch(void* const* d_in, const int* in_sizes, int n_in,
                              void* d_out, int out_size, void* d_ws, size_t ws_size,
                              hipStream_t stream) {
    const float* C = (const float*)d_in[0];
    float* out = (float*)d_out;
    dp_softmin_wave<<<256, 64, 0, stream>>>(C, out);
}

// Round 21
// 68.027 us; speedup vs baseline: 1.7456x; 1.7456x over previous
//
#include <hip/hip_runtime.h>

#define S 256
#define L2E 1.44269504088896340736f   // log2(e)
#define LN2 0.69314718055994530942f

// Raw HW transcendentals: v_exp_f32 = 2^x, v_log_f32 = log2(x).
#define EXP2F(x) __builtin_amdgcn_exp2f(x)
#define LOG2F(x) __builtin_amdgcn_logf(x)

// Probability-domain soft-min DP; R17 machine with the step re-ordered to
// remove two exposed-latency hazards found by audit:
//  (1) DIRECT slot refill `sP = *(ptr)` -- R11..R17 wrote `ld = *(ptr);
//      ... sP = ld;`: if not reg-coalesced, that copy forces a same-step
//      vmcnt(0) on the just-issued load (~300cy exposed EVERY step --
//      explains the 318cy/step plateau, depth-insensitivity, VGPR=80).
//  (2) boundary cell e3 + ds_bpermute issued at step START (inputs ready
//      at entry), conversions/exp2 fill its ~120cy shadow; consumer is
//      next step's e0.
// Semantics byte-identical to R17 (verified absmax 0): same cols, clamps,
// junk masks, renorm every 64 diags (exact 2^-e, sig -= e), same init.

typedef float f4 __attribute__((ext_vector_type(4)));

template <int I> __device__ __forceinline__ float comp(const f4 v) {
    if constexpr (I == 0) return v.x;
    else if constexpr (I == 1) return v.y;
    else if constexpr (I == 2) return v.z;
    else return v.w;
}

__device__ __forceinline__ f4 g4f(const f4 v) {
    f4 r;
    r.x = EXP2F(v.x * -L2E); r.y = EXP2F(v.y * -L2E);
    r.z = EXP2F(v.z * -L2E); r.w = EXP2F(v.w * -L2E);
    return r;
}

template <int P, int SB>
__device__ __forceinline__ void stepf(
    int kk, int t, int t4, const float* __restrict__ Cb,
    int rb0, int rb1, int rb2, int rb3,
    f4& c0, f4& c1, f4& c2, f4& c3,
    f4& n0, f4& n1, f4& n2, f4& n3,
    f4& s00, f4& s01, f4& s02, f4& s03,
    f4& s10, f4& s11, f4& s12, f4& s13,
    f4& s20, f4& s21, f4& s22, f4& s23,
    f4& s30, f4& s31, f4& s32, f4& s33,
    float& w10, float& w11, float& w12, float& w13,
    float& w20, float& w21, float& w22, float& w23,
    float& pd1, float& pd2)
{
    const int colr = kk + (20 - P) - t4;
    const int col  = colr < 0 ? 0 : (colr > 252 ? 252 : colr);
    const int rb   = (P == 0) ? rb0 : (P == 1) ? rb1 : (P == 2) ? rb2 : rb3;

    f4& cP = (P == 0) ? c0 : (P == 1) ? c1 : (P == 2) ? c2 : c3;
    f4& nP = (P == 0) ? n0 : (P == 1) ? n1 : (P == 2) ? n2 : n3;
    f4& sP =
        (SB == 0) ? ((P == 0) ? s00 : (P == 1) ? s01 : (P == 2) ? s02 : s03)
      : (SB == 1) ? ((P == 0) ? s10 : (P == 1) ? s11 : (P == 2) ? s12 : s13)
      : (SB == 2) ? ((P == 0) ? s20 : (P == 1) ? s21 : (P == 2) ? s22 : s23)
                  : ((P == 0) ? s30 : (P == 1) ? s31 : (P == 2) ? s32 : s33);

    // (a) rotate early -- register move, independent of this step's exp2
    cP = nP;

    // (b) boundary cell first, bpermute issued at step start
    const float g3 = comp<(P + 1) & 3>(c3);
    const float e3 = g3 * (w13 + w12 + w22);
    const float nx = __shfl_up(e3, 1);

    const float g0 = comp<(P    ) & 3>(c0);
    const float g1 = comp<(P + 3) & 3>(c1);
    const float g2 = comp<(P + 2) & 3>(c2);
    const float e0 = g0 * (w10 + pd1 + pd2);
    const float e1 = g1 * (w11 + w10 + w20);
    const float e2 = g2 * (w12 + w11 + w21);

    // (c) conversion of the slot loaded 16 steps ago (fills bperm shadow),
    //     then DIRECT refill: the load writes sP's registers, no copy.
    const bool junk = (colr > 268);
    f4 gq;
    gq.x = junk ? 0.0f : EXP2F(sP.x * -L2E);
    gq.y = junk ? 0.0f : EXP2F(sP.y * -L2E);
    gq.z = junk ? 0.0f : EXP2F(sP.z * -L2E);
    gq.w = junk ? 0.0f : EXP2F(sP.w * -L2E);
    nP = gq;
    sP = *(const f4*)(Cb + rb + col);

    // (d) state update
    w20 = w10; w21 = w11; w22 = w12; w23 = w13;
    w10 = e0;  w11 = e1;  w12 = e2;  w13 = e3;
    pd2 = pd1;
    pd1 = (t == 0) ? 0.0f : nx;

    // step boundary: loads may not sink across a may-store asm
    asm volatile("" ::: "memory");
}

__global__ __launch_bounds__(64, 1) void dp_softmin_wave(const float* __restrict__ C,
                                                         float* __restrict__ out) {
    const int b = blockIdx.x;
    const int t = threadIdx.x;
    const float* Cb = C + ((size_t)b << 16);
    const int t4 = 4 * t;

    const int rb0 = (t4 + 0) << 8;
    const int rb1 = (t4 + 1) << 8;
    const int rb2 = (t4 + 2) << 8;
    const int rb3 = (t4 + 3) << 8;

    auto cl = [](int c) { return c < 0 ? 0 : (c > 252 ? 252 : c); };
    auto q4 = [&](int rb, int col) { return *(const f4*)(Cb + rb + col); };

    // init = fixed point of the unconditional machine for kk <= 0 (R12/R17)
    f4 c0 = g4f(q4(rb0, 0)), c1 = g4f(q4(rb1, 0)),
       c2 = g4f(q4(rb2, 0)), c3 = g4f(q4(rb3, 0));
    f4 n0 = g4f(q4(rb0, cl(4 - t4)));
    f4 n1 = c1, n2 = c2, n3 = c3;

    f4 s00 = q4(rb0, cl(20 - t4));
    f4 s01 = q4(rb1, cl(4 - t4));
    f4 s02 = q4(rb2, cl(4 - t4));
    f4 s03 = q4(rb3, cl(4 - t4));
    f4 s10 = q4(rb0, cl(8 - t4)),  s11 = q4(rb1, cl(8 - t4));
    f4 s12 = q4(rb2, cl(8 - t4)),  s13 = q4(rb3, cl(8 - t4));
    f4 s20 = q4(rb0, cl(12 - t4)), s21 = q4(rb1, cl(12 - t4));
    f4 s22 = q4(rb2, cl(12 - t4)), s23 = q4(rb3, cl(12 - t4));
    f4 s30 = q4(rb0, cl(16 - t4)), s31 = q4(rb1, cl(16 - t4));
    f4 s32 = q4(rb2, cl(16 - t4)), s33 = q4(rb3, cl(16 - t4));

    float w10 = 0.0f, w11 = 0.0f, w12 = 0.0f, w13 = 0.0f;
    float w20 = 0.0f, w21 = 0.0f, w22 = 0.0f, w23 = 0.0f;
    float pd1 = 0.0f, pd2 = 0.0f;
    int sig = 0;

    if (t == 0) w10 = c0.x;                // seed: w(0,0) = g(0,0)

    asm volatile("" ::: "memory");          // pin init loads above the chain

#define ARGS t, t4, Cb, rb0, rb1, rb2, rb3, c0,c1,c2,c3, n0,n1,n2,n3, \
             s00,s01,s02,s03, s10,s11,s12,s13, s20,s21,s22,s23, s30,s31,s32,s33, \
             w10,w11,w12,w13, w20,w21,w22,w23, pd1,pd2

    // prologue kk = 1..15
    stepf<1,0>(1, ARGS);  stepf<2,0>(2, ARGS);  stepf<3,0>(3, ARGS);
    stepf<0,1>(4, ARGS);  stepf<1,1>(5, ARGS);  stepf<2,1>(6, ARGS);  stepf<3,1>(7, ARGS);
    stepf<0,2>(8, ARGS);  stepf<1,2>(9, ARGS);  stepf<2,2>(10, ARGS); stepf<3,2>(11, ARGS);
    stepf<0,3>(12, ARGS); stepf<1,3>(13, ARGS); stepf<2,3>(14, ARGS); stepf<3,3>(15, ARGS);

#pragma clang loop unroll(disable)
    for (int kb = 16; kb <= 480; kb += 16) {
        if ((kb & 63) == 0) {
            // block-floating renorm: exact power-of-2, sig -= e
            float M = fmaxf(fmaxf(fmaxf(w10, w11), fmaxf(w12, w13)),
                            fmaxf(fmaxf(w20, w21), fmaxf(w22, w23)));
            #pragma unroll
            for (int m = 1; m < 64; m <<= 1) M = fmaxf(M, __shfl_xor(M, m));
            int e = ((__float_as_int(M) >> 23) & 255) - 127;
            float f = __int_as_float((127 - e) << 23);
            w10 *= f; w11 *= f; w12 *= f; w13 *= f;
            w20 *= f; w21 *= f; w22 *= f; w23 *= f;
            pd1 *= f; pd2 *= f;
            sig -= e;
        }
        stepf<0,0>(kb + 0, ARGS);  stepf<1,0>(kb + 1, ARGS);
        stepf<2,0>(kb + 2, ARGS);  stepf<3,0>(kb + 3, ARGS);
        stepf<0,1>(kb + 4, ARGS);  stepf<1,1>(kb + 5, ARGS);
        stepf<2,1>(kb + 6, ARGS);  stepf<3,1>(kb + 7, ARGS);
        stepf<0,2>(kb + 8, ARGS);  stepf<1,2>(kb + 9, ARGS);
        stepf<2,2>(kb + 10, ARGS); stepf<3,2>(kb + 11, ARGS);
        stepf<0,3>(kb + 12, ARGS); stepf<1,3>(kb + 13, ARGS);
        stepf<2,3>(kb + 14, ARGS); stepf<3,3>(kb + 15, ARGS);
    }

    // epilogue kk = 496..510
    stepf<0,0>(496, ARGS); stepf<1,0>(497, ARGS); stepf<2,0>(498, ARGS); stepf<3,0>(499, ARGS);
    stepf<0,1>(500, ARGS); stepf<1,1>(501, ARGS); stepf<2,1>(502, ARGS); stepf<3,1>(503, ARGS);
    stepf<0,2>(504, ARGS); stepf<1,2>(505, ARGS); stepf<2,2>(506, ARGS); stepf<3,2>(507, ARGS);
    stepf<0,3>(508, ARGS); stepf<1,3>(509, ARGS); stepf<2,3>(510, ARGS);
#undef ARGS

    // corner cell (255,255): lane 63, E = sig - log2(w13), D = E * ln2
    if (t == 63) out[b] = ((float)sig - LOG2F(w13)) * LN2;
}

extern "C" void kernel_launch(void* const* d_in, const int* in_sizes, int n_in,
                              void* d_out, int out_size, void* d_ws, size_t ws_size,
                              hipStream_t stream) {
    const float* C = (const float*)d_in[0];
    float* out = (float*)d_out;
    dp_softmin_wave<<<512, 64, 0, stream>>>(C, out);
}